// Round 6
// baseline (449.366 us; speedup 1.0000x reference)
//
#include <hip/hip_runtime.h>
#include <hip/hip_bf16.h>

#define MAX_DIST 32.0f
#define BOX 129

typedef __attribute__((ext_vector_type(4))) float f4;

// One thread per (point, float4-quad). 8 lanes per point:
//  - coords read once per 8 lanes (L1 broadcast), 1/4 the decode VALU of R1
//  - feature read: one nontemporal float4 per lane = 128B/point coalesced,
//    bypassing L2 so the 64MB use-once stream doesn't evict the hot atomic
//    region (~45MB vs 32MB L2)
//  - 4 fire-and-forget f32 atomics per lane into one 128B cell line
__global__ void __launch_bounds__(256) scatter_kernel(
    const float* __restrict__ coords,
    const f4* __restrict__ feats4,
    float* __restrict__ grid,
    int N) {
  int t = blockIdx.x * blockDim.x + threadIdx.x;
  if (t >= N * 8) return;
  int p = t >> 3;
  int q = t & 7;
  float x = coords[3 * p + 0];
  float y = coords[3 * p + 1];
  float z = coords[3 * p + 2];
  // (c + 32) / 0.5 == (c + 32) * 2 (exact); round-half-even matches jnp.round
  int gx = __float2int_rn((x + MAX_DIST) * 2.0f);
  int gy = __float2int_rn((y + MAX_DIST) * 2.0f);
  int gz = __float2int_rn((z + MAX_DIST) * 2.0f);
  if ((unsigned)gx < BOX && (unsigned)gy < BOX && (unsigned)gz < BOX) {
    f4 v = __builtin_nontemporal_load(feats4 + (long)p * 8 + q);
    long base = (((long)gx * BOX + gy) * BOX + gz) * 32 + 4 * q;
    atomicAdd(&grid[base + 0], v.x);
    atomicAdd(&grid[base + 1], v.y);
    atomicAdd(&grid[base + 2], v.z);
    atomicAdd(&grid[base + 3], v.w);
  }
}

extern "C" void kernel_launch(void* const* d_in, const int* in_sizes, int n_in,
                              void* d_out, int out_size, void* d_ws, size_t ws_size,
                              hipStream_t stream) {
  const float* coords = (const float*)d_in[0];
  const f4* feats4    = (const f4*)d_in[1];
  float* grid = (float*)d_out;

  int N = in_sizes[0] / 3;  // 500000

  // Zero the output grid. memset fill is the PROVEN-safe zero-before-atomics
  // pattern (non-temporal writes, visible to device-scope atomics); a plain
  // store kernel here corrupts results under graph replay (round-2 failure:
  // dirty per-XCD L2 lines clobber atomic RMWs on eviction).
  hipMemsetAsync(d_out, 0, (size_t)out_size * sizeof(float), stream);

  int total = N * 8;
  int blocks = (total + 255) / 256;
  scatter_kernel<<<blocks, 256, 0, stream>>>(coords, feats4, grid, N);
}

// Round 7
// 371.985 us; speedup vs baseline: 1.2080x; 1.2080x over previous
//
#include <hip/hip_runtime.h>
#include <hip/hip_bf16.h>

#define MAX_DIST 32.0f
#define BOX 129

// One thread per (point, float-pair). 16 consecutive lanes per point:
//  - coalesced float2 feature reads (8B/lane, 128B/point)
//  - ONE packed 2xf32 atomic per lane; a wave-instruction's 64 lanes cover
//    4 points x one full 128B cell line each (contiguous within line).
//    R1-vs-R6 showed atomic cost tracks distinct-lines-per-instruction:
//    keep lanes contiguous within a cell's line. Packing halves the
//    atomic request count (16M -> 8M) at identical line coverage.
__global__ void __launch_bounds__(256) scatter_kernel(
    const float* __restrict__ coords,
    const float2* __restrict__ feats2,
    float* __restrict__ grid,
    int N) {
  int total = N * 16;
  int stride = gridDim.x * blockDim.x;
  for (int t = blockIdx.x * blockDim.x + threadIdx.x; t < total; t += stride) {
    int p = t >> 4;
    int fp = t & 15;
    float x = coords[3 * p + 0];
    float y = coords[3 * p + 1];
    float z = coords[3 * p + 2];
    // (c + 32) / 0.5 == (c + 32) * 2 (exact); round-half-even matches jnp.round
    int gx = __float2int_rn((x + MAX_DIST) * 2.0f);
    int gy = __float2int_rn((y + MAX_DIST) * 2.0f);
    int gz = __float2int_rn((z + MAX_DIST) * 2.0f);
    if ((unsigned)gx < BOX && (unsigned)gy < BOX && (unsigned)gz < BOX) {
      float2 v = feats2[(long)p * 16 + fp];
      float* g = &grid[(((long)gx * BOX + gy) * BOX + gz) * 32 + 2 * fp];
#if __has_builtin(__builtin_amdgcn_global_atomic_fadd_v2f32)
      typedef __attribute__((ext_vector_type(2))) float vf2;
      vf2 pv; pv.x = v.x; pv.y = v.y;
      __builtin_amdgcn_global_atomic_fadd_v2f32((vf2*)g, pv);
#else
      atomicAdd(&g[0], v.x);
      atomicAdd(&g[1], v.y);
#endif
    }
  }
}

extern "C" void kernel_launch(void* const* d_in, const int* in_sizes, int n_in,
                              void* d_out, int out_size, void* d_ws, size_t ws_size,
                              hipStream_t stream) {
  const float* coords  = (const float*)d_in[0];
  const float2* feats2 = (const float2*)d_in[1];
  float* grid = (float*)d_out;

  int N = in_sizes[0] / 3;  // 500000

  // Zero the output grid. memset fill is the PROVEN-safe zero-before-atomics
  // pattern; a plain store kernel here corrupts results under graph replay
  // (round-2 failure: dirty per-XCD L2 lines clobber atomic RMWs).
  hipMemsetAsync(d_out, 0, (size_t)out_size * sizeof(float), stream);

  int total = N * 16;
  int blocks = 4096;
  if (blocks > (total + 255) / 256) blocks = (total + 255) / 256;
  scatter_kernel<<<blocks, 256, 0, stream>>>(coords, feats2, grid, N);
}